// Round 17
// baseline (817.334 us; speedup 1.0000x reference)
//
#include <hip/hip_runtime.h>
#include <math.h>

#define NA    360
#define ZPT   8
#define CROWS 24            // staged v-rows (24-row window proven R5-R14)
#define CPITCH 64           // cells per row (u-window 52 proven; 64 staged)
#define NCELL (CROWS*CPITCH)   // 1536 cells = 12 KB per buffer
#define VLO_MAX 232         // staged rows vlo..vlo+23 <= 255
#define ULO_MAX 192         // ui <= 62 -> ui+1 tap stays in-row (R15 bug: 191)
#define BSTRIDE 94371840    // bytes per batch slab = 360*65536*4

// Cone-beam backprojection, batch-fused, interleaved {b0,b1} float2 cells,
// taps = 2x ds_read2_b64 per k. R16 diagnosis: both VALU (46%) and LDS (44%)
// pipes half-idle, wall ~= sum -> latency-bound dependent chain per k.
// R17: two-phase compute - issue ALL 16 tap-reads of the angle into static
// register arrays (one lgkmcnt region), then all FMAs; pays LDS latency once
// per angle instead of 8x. Staging stays global_load_lds ONLY (R13 lesson).
// ULO_MAX=192 LOAD-BEARING (R15: 191 -> wrap, absmax 9.5).
// Geometry: dz=dy=dx=2mm, dv=du=2mm, DSO=1000, DSD=1536, mag in [1.302,1.872];
// iv in (8.6,246.4) -> v never clamps, v0+1 in-bounds; 24-row/52-col window
// coverage proven exhaustively R5-R16 (absmax 0.25 stable).

typedef float v2f __attribute__((ext_vector_type(2)));
typedef __attribute__((address_space(1))) const void gas_t;
typedef __attribute__((address_space(3))) void las_t;

__device__ __forceinline__ int2 bbox_angle(float c, float s,
    float xclo, float xchi, float yclo, float ychi, float zvlo, float zvhi)
{
    const float a0 = xclo*c, a1 = xchi*c, b0 = yclo*s, b1 = ychi*s;
    const float xr0 = a0+b0, xr1 = a0+b1, xr2 = a1+b0, xr3 = a1+b1;
    const float xmn = fminf(fminf(xr0,xr1), fminf(xr2,xr3));
    const float xmx = fmaxf(fmaxf(xr0,xr1), fmaxf(xr2,xr3));
    const float c0 = yclo*c, c1 = ychi*c, d0 = xclo*s, d1 = xchi*s;
    const float yr0 = c0-d0, yr1 = c0-d1, yr2 = c1-d0, yr3 = c1-d1;
    const float ymn = fminf(fminf(yr0,yr1), fminf(yr2,yr3));
    const float ymx = fmaxf(fmaxf(yr0,yr1), fmaxf(yr2,yr3));
    const float mlo = 1536.f * __builtin_amdgcn_rcpf(1000.f - xmn);
    const float mhi = 1536.f * __builtin_amdgcn_rcpf(1000.f - xmx);
    const float umn = fminf(fminf(ymn*mlo, ymn*mhi), fminf(ymx*mlo, ymx*mhi));
    int u_lo = (int)floorf(fmaf(umn, 0.5f, 127.5f)) - 1;
    u_lo = u_lo < 0 ? 0 : (u_lo > ULO_MAX ? ULO_MAX : u_lo);
    const float vmn = fminf(fminf(zvlo*mlo, zvlo*mhi), fminf(zvhi*mlo, zvhi*mhi));
    int v_lo = (int)floorf(vmn + 127.5f) - 1;
    v_lo = v_lo < 0 ? 0 : (v_lo > VLO_MAX ? VLO_MAX : v_lo);
    return make_int2(u_lo, v_lo);
}

// Wave w stages buffer dwords [w*768 .. w*768+767] (12 width-4 gl_lds).
__device__ __forceinline__ void stage12(const char* gb, float* ldsw,
                                        const int goffB[12]) {
    #pragma unroll
    for (int i = 0; i < 12; ++i) {
        __builtin_amdgcn_global_load_lds(
            (gas_t*)(gb + goffB[i]),
            (las_t*)(ldsw + i * 64), 4, 0, 0);
    }
}

__device__ __forceinline__ void compute_angle(const v2f* __restrict__ smb,
    float c, float s, float xc, float yc, float zf0, int u_lo, int v_lo,
    v2f acc[ZPT])
{
    const float xr  = xc*c + yc*s;
    const float yr  = yc*c - xc*s;
    const float mag = 1536.f * __builtin_amdgcn_rcpf(1000.f - xr);
    const float iu  = fmaf(yr*mag, 0.5f, 127.5f);
    const bool uval = (iu >= 0.f) && (iu <= 255.f);
    const float iuc = fminf(fmaxf(iu, 0.f), 255.f);
    int u0 = (int)iuc; u0 = u0 > 254 ? 254 : u0;
    const float fu  = iuc - (float)u0;
    const float w   = uval ? 1.f : 0.f;
    const float wu1 = fu*w, wu0 = w - wu1;
    const v2f   w0v = {wu0, wu0};
    const v2f   w1v = {wu1, wu1};
    const int   ui  = u0 - u_lo;                         // <= 62 for valid taps
    const float ivb = fmaf(zf0, mag, 127.5f) - (float)v_lo;

    // Phase 1: all addresses + all 16 ds_read2_b64 into static reg arrays.
    v2f c00[ZPT], c01[ZPT], c10[ZPT], c11[ZPT];
    float fvs[ZPT];
    #pragma unroll
    for (int k = 0; k < ZPT; ++k) {
        const float ivl = fmaf((float)k, mag, ivb);
        const int   v0  = (int)ivl;                      // >0 -> trunc==floor
        fvs[k] = __builtin_amdgcn_fractf(ivl);
        const v2f* cell = smb + ((v0 << 6) + ui);
        c00[k] = cell[0];                                // {b0,b1}@(v0,  u0)
        c10[k] = cell[CPITCH];                           // (v0+1,u0)
        c01[k] = cell[1];                                // (v0,  u0+1)
        c11[k] = cell[CPITCH+1];                         // (v0+1,u0+1)
    }
    // Phase 2: all FMAs (reads already in flight / landed).
    #pragma unroll
    for (int k = 0; k < ZPT; ++k) {
        const v2f fvv = {fvs[k], fvs[k]};
        const v2f q0 = __builtin_elementwise_fma(fvv, c10[k] - c00[k], c00[k]);
        const v2f q1 = __builtin_elementwise_fma(fvv, c11[k] - c01[k], c01[k]);
        acc[k] = __builtin_elementwise_fma(w0v, q0, acc[k]);
        acc[k] = __builtin_elementwise_fma(w1v, q1, acc[k]);
    }
}

__global__ __launch_bounds__(256, 4) void bp_kernel(const float* __restrict__ proj,
                                                    float* __restrict__ out) {
    __shared__ float2 cs_sh[NA];
    __shared__ int2   bb_sh[NA];
    __shared__ v2f    patch[2][NCELL];   // interleaved {b0,b1} cells

    const int tid = threadIdx.y * 16 + threadIdx.x;

    const int zg = blockIdx.x;            // z-group (16)
    const int t  = blockIdx.y;            // xy tile (64)
    const int x0 = (t & 7) * 16;
    const int y0 = (t >> 3) * 16;
    const int zb = zg * ZPT;

    const float zf0  = (float)zb - 63.5f;
    const float xclo = ((float)x0 - 63.5f) * 2.f, xchi = xclo + 30.f;
    const float yclo = ((float)y0 - 63.5f) * 2.f, ychi = yclo + 30.f;

    for (int i = tid; i < NA; i += 256) {
        float th = (float)i * (float)(2.0 * M_PI / (double)NA);
        float sv, cv; sincosf(th, &sv, &cv);
        cs_sh[i] = make_float2(cv, sv);
        bb_sh[i] = bbox_angle(cv, sv, xclo, xchi, yclo, ychi, zf0, zf0 + 7.f);
    }
    __syncthreads();

    // per-lane staging source offsets (constant across angles):
    // buffer dword f = wv*768 + i*64 + lane -> batch=f&1, ucol=(f>>1)&63,
    // v=f>>7. Source = angle origin + batch*BSTRIDE + v*1024 + ucol*4.
    const int wv   = tid >> 6;
    const int lane = tid & 63;
    int goffB[12];
    #pragma unroll
    for (int i = 0; i < 12; ++i) {
        const int f    = wv * 768 + i * 64 + lane;
        const int bsel = f & 1;
        const int ucol = (f >> 1) & 63;
        const int v    = f >> 7;
        goffB[i] = bsel * BSTRIDE + v * 1024 + ucol * 4;
    }

    const char* projB = (const char*)proj;
    const float xc = ((float)(x0 + threadIdx.x) - 63.5f) * 2.f;
    const float yc = ((float)(y0 + threadIdx.y) - 63.5f) * 2.f;

    float* l0 = (float*)&patch[0][0] + wv * 768;
    float* l1 = (float*)&patch[1][0] + wv * 768;

    v2f acc[ZPT];
    #pragma unroll
    for (int k = 0; k < ZPT; ++k) acc[k] = (v2f){0.f, 0.f};

    // prologue: stage angle 0 into patch[0]
    {
        const int2 lo = bb_sh[0];
        const uint32_t aoff = __builtin_amdgcn_readfirstlane(
            ((uint32_t)lo.y << 10) + ((uint32_t)lo.x << 2));
        stage12(projB + aoff, l0, goffB);
    }
    __syncthreads();   // implicit vmcnt(0) drain -> patch[0] ready

    for (int a = 0; a < NA; a += 2) {
        {   // stage a+1 -> patch[1] while computing a from patch[0]
            const int2 lo = bb_sh[a + 1];
            const uint32_t aoff = __builtin_amdgcn_readfirstlane(
                (uint32_t)(a + 1) * 262144u +
                ((uint32_t)lo.y << 10) + ((uint32_t)lo.x << 2));
            stage12(projB + aoff, l1, goffB);
        }
        {
            const float2 cs = cs_sh[a];
            const int2   lo = bb_sh[a];
            compute_angle(patch[0], cs.x, cs.y, xc, yc, zf0, lo.x, lo.y, acc);
        }
        __syncthreads();
        if (a + 2 < NA) {   // stage a+2 -> patch[0] while computing a+1
            const int2 lo = bb_sh[a + 2];
            const uint32_t aoff = __builtin_amdgcn_readfirstlane(
                (uint32_t)(a + 2) * 262144u +
                ((uint32_t)lo.y << 10) + ((uint32_t)lo.x << 2));
            stage12(projB + aoff, l0, goffB);
        }
        {
            const float2 cs = cs_sh[a + 1];
            const int2   lo = bb_sh[a + 1];
            compute_angle(patch[1], cs.x, cs.y, xc, yc, zf0, lo.x, lo.y, acc);
        }
        __syncthreads();
    }

    float* o0 = out + (((size_t)zb) * 128 + (y0 + threadIdx.y)) * 128
                    + (x0 + threadIdx.x);
    float* o1 = o0 + (size_t)128 * 128 * 128;   // batch 1 volume
    #pragma unroll
    for (int k = 0; k < ZPT; ++k) {
        o0[(size_t)k * (128 * 128)] = acc[k].x;
        o1[(size_t)k * (128 * 128)] = acc[k].y;
    }
}

extern "C" void kernel_launch(void* const* d_in, const int* in_sizes, int n_in,
                              void* d_out, int out_size, void* d_ws, size_t ws_size,
                              hipStream_t stream) {
    const float* proj = (const float*)d_in[0];
    float* out = (float*)d_out;
    dim3 grid(128 / ZPT, 64, 1);   // (z-groups, xy-tiles) = 1024 blocks, batch fused
    dim3 block(16, 16, 1);
    hipLaunchKernelGGL(bp_kernel, grid, block, 0, stream, proj, out);
}

// Round 18
// 773.508 us; speedup vs baseline: 1.0567x; 1.0567x over previous
//
#include <hip/hip_runtime.h>
#include <math.h>

#define NA    360
#define ZPT   8
#define CROWS 24            // staged v-rows (24-row window proven R5-R14)
#define CPITCH 52           // cells per row: 52*8B=416B stride -> banks spread by v0
                            // (20*v0 mod 32; the only pitch that ever halved conflicts: R6)
#define NCELLP 1280         // padded cells (staging writes 2560 dwords; reads use 1248)
#define VLO_MAX 231         // padded staging row v_lo+24 stays in-slab (R6 value)
#define ULO_MAX 204         // ui <= 50 -> ui+1 tap <= 51 in 52-col row (R6-proven window)
#define BSTRIDE 94371840    // bytes per batch slab = 360*65536*4

// Cone-beam backprojection, batch-fused, interleaved {b0,b1} float2 cells,
// taps = 2x ds_read2_b64 per k (offsets {0,52},{1,53}). Staging stays
// global_load_lds ONLY (R13: register-staged scatter -> FETCH 16GB).
// R18 change vs R16: cell pitch 64 -> 52. Empirical conflict table:
// pitch 52 f32 (R6/R7) = 7.1e7 cyc; every 64/65/66-based layout since
// (R8-R17) = 1.36-1.52e8. Row stride 64 cells = 512B = 0 mod 32 banks ->
// v0 contributes nothing to bank spread; 52 cells = 416B -> rows shift by
// 4 bank-pairs. Window geometry is R6's exhaustively-proven one.
// Geometry: dz=dy=dx=2mm, dv=du=2mm, DSO=1000, DSD=1536, mag in [1.302,1.872];
// iv in (8.6,246.4) -> v never clamps, v0+1 in-bounds; v0-vlo in [0,22].

typedef float v2f __attribute__((ext_vector_type(2)));
typedef __attribute__((address_space(1))) const void gas_t;
typedef __attribute__((address_space(3))) void las_t;

__device__ __forceinline__ int2 bbox_angle(float c, float s,
    float xclo, float xchi, float yclo, float ychi, float zvlo, float zvhi)
{
    const float a0 = xclo*c, a1 = xchi*c, b0 = yclo*s, b1 = ychi*s;
    const float xr0 = a0+b0, xr1 = a0+b1, xr2 = a1+b0, xr3 = a1+b1;
    const float xmn = fminf(fminf(xr0,xr1), fminf(xr2,xr3));
    const float xmx = fmaxf(fmaxf(xr0,xr1), fmaxf(xr2,xr3));
    const float c0 = yclo*c, c1 = ychi*c, d0 = xclo*s, d1 = xchi*s;
    const float yr0 = c0-d0, yr1 = c0-d1, yr2 = c1-d0, yr3 = c1-d1;
    const float ymn = fminf(fminf(yr0,yr1), fminf(yr2,yr3));
    const float ymx = fmaxf(fmaxf(yr0,yr1), fmaxf(yr2,yr3));
    const float mlo = 1536.f * __builtin_amdgcn_rcpf(1000.f - xmn);
    const float mhi = 1536.f * __builtin_amdgcn_rcpf(1000.f - xmx);
    const float umn = fminf(fminf(ymn*mlo, ymn*mhi), fminf(ymx*mlo, ymx*mhi));
    int u_lo = (int)floorf(fmaf(umn, 0.5f, 127.5f)) - 1;
    u_lo = u_lo < 0 ? 0 : (u_lo > ULO_MAX ? ULO_MAX : u_lo);
    const float vmn = fminf(fminf(zvlo*mlo, zvlo*mhi), fminf(zvhi*mlo, zvhi*mhi));
    int v_lo = (int)floorf(vmn + 127.5f) - 1;
    v_lo = v_lo < 0 ? 0 : (v_lo > VLO_MAX ? VLO_MAX : v_lo);
    return make_int2(u_lo, v_lo);
}

// Wave w stages buffer dwords [w*640 .. w*640+639] (10 width-4 gl_lds).
__device__ __forceinline__ void stage10(const char* gb, float* ldsw,
                                        const int goffB[10]) {
    #pragma unroll
    for (int i = 0; i < 10; ++i) {
        __builtin_amdgcn_global_load_lds(
            (gas_t*)(gb + goffB[i]),
            (las_t*)(ldsw + i * 64), 4, 0, 0);
    }
}

__device__ __forceinline__ void compute_angle(const v2f* __restrict__ smb,
    float c, float s, float xc, float yc, float zf0, int u_lo, int v_lo,
    v2f acc[ZPT])
{
    const float xr  = xc*c + yc*s;
    const float yr  = yc*c - xc*s;
    const float mag = 1536.f * __builtin_amdgcn_rcpf(1000.f - xr);
    const float iu  = fmaf(yr*mag, 0.5f, 127.5f);
    const bool uval = (iu >= 0.f) && (iu <= 255.f);
    const float iuc = fminf(fmaxf(iu, 0.f), 255.f);
    int u0 = (int)iuc; u0 = u0 > 254 ? 254 : u0;
    const float fu  = iuc - (float)u0;
    const float w   = uval ? 1.f : 0.f;
    const float wu1 = fu*w, wu0 = w - wu1;
    const v2f   w0v = {wu0, wu0};
    const v2f   w1v = {wu1, wu1};
    const int   ui  = u0 - u_lo;                         // <= 50 for valid taps
    const float ivb = fmaf(zf0, mag, 127.5f) - (float)v_lo;
    #pragma unroll
    for (int k = 0; k < ZPT; ++k) {
        const float ivl = fmaf((float)k, mag, ivb);
        const int   v0  = (int)ivl;                      // >0 -> trunc==floor
        const float fv  = __builtin_amdgcn_fractf(ivl);
        const v2f* cell = smb + (v0 * CPITCH + ui);
        const v2f c00 = cell[0];                         // {b0,b1}@(v0,  u0)
        const v2f c10 = cell[CPITCH];                    // (v0+1,u0)   read2_b64
        const v2f c01 = cell[1];                         // (v0,  u0+1)
        const v2f c11 = cell[CPITCH+1];                  // (v0+1,u0+1) read2_b64
        const v2f fvv = {fv, fv};
        const v2f q0 = __builtin_elementwise_fma(fvv, c10 - c00, c00);
        const v2f q1 = __builtin_elementwise_fma(fvv, c11 - c01, c01);
        acc[k] = __builtin_elementwise_fma(w0v, q0, acc[k]);
        acc[k] = __builtin_elementwise_fma(w1v, q1, acc[k]);
    }
}

__global__ __launch_bounds__(256, 4) void bp_kernel(const float* __restrict__ proj,
                                                    float* __restrict__ out) {
    __shared__ float2 cs_sh[NA];
    __shared__ int2   bb_sh[NA];
    __shared__ v2f    patch[2][NCELLP];   // interleaved {b0,b1} cells (padded)

    const int tid = threadIdx.y * 16 + threadIdx.x;

    const int zg = blockIdx.x;            // z-group (16)
    const int t  = blockIdx.y;            // xy tile (64)
    const int x0 = (t & 7) * 16;
    const int y0 = (t >> 3) * 16;
    const int zb = zg * ZPT;

    const float zf0  = (float)zb - 63.5f;
    const float xclo = ((float)x0 - 63.5f) * 2.f, xchi = xclo + 30.f;
    const float yclo = ((float)y0 - 63.5f) * 2.f, ychi = yclo + 30.f;

    for (int i = tid; i < NA; i += 256) {
        float th = (float)i * (float)(2.0 * M_PI / (double)NA);
        float sv, cv; sincosf(th, &sv, &cv);
        cs_sh[i] = make_float2(cv, sv);
        bb_sh[i] = bbox_angle(cv, sv, xclo, xchi, yclo, ychi, zf0, zf0 + 7.f);
    }
    __syncthreads();

    // per-lane staging source offsets (constant across angles):
    // buffer dword f = wv*640 + i*64 + lane -> batch=f&1, cell=f>>1,
    // v=cell/52, ucol=cell%52. Source = angle origin + batch*BSTRIDE
    // + v*1024 + ucol*4. Padded cells (>=1248) read row v_lo+24 (in-slab).
    const int wv   = tid >> 6;
    const int lane = tid & 63;
    int goffB[10];
    #pragma unroll
    for (int i = 0; i < 10; ++i) {
        const int f    = wv * 640 + i * 64 + lane;
        const int bsel = f & 1;
        const int cidx = f >> 1;
        const int v    = cidx / 52;           // init-only exact division
        const int ucol = cidx - v * 52;
        goffB[i] = bsel * BSTRIDE + v * 1024 + ucol * 4;
    }

    const char* projB = (const char*)proj;
    const float xc = ((float)(x0 + threadIdx.x) - 63.5f) * 2.f;
    const float yc = ((float)(y0 + threadIdx.y) - 63.5f) * 2.f;

    float* l0 = (float*)&patch[0][0] + wv * 640;
    float* l1 = (float*)&patch[1][0] + wv * 640;

    v2f acc[ZPT];
    #pragma unroll
    for (int k = 0; k < ZPT; ++k) acc[k] = (v2f){0.f, 0.f};

    // prologue: stage angle 0 into patch[0]
    {
        const int2 lo = bb_sh[0];
        const uint32_t aoff = __builtin_amdgcn_readfirstlane(
            ((uint32_t)lo.y << 10) + ((uint32_t)lo.x << 2));
        stage10(projB + aoff, l0, goffB);
    }
    __syncthreads();   // implicit vmcnt(0) drain -> patch[0] ready

    for (int a = 0; a < NA; a += 2) {
        {   // stage a+1 -> patch[1] while computing a from patch[0]
            const int2 lo = bb_sh[a + 1];
            const uint32_t aoff = __builtin_amdgcn_readfirstlane(
                (uint32_t)(a + 1) * 262144u +
                ((uint32_t)lo.y << 10) + ((uint32_t)lo.x << 2));
            stage10(projB + aoff, l1, goffB);
        }
        {
            const float2 cs = cs_sh[a];
            const int2   lo = bb_sh[a];
            compute_angle(patch[0], cs.x, cs.y, xc, yc, zf0, lo.x, lo.y, acc);
        }
        __syncthreads();
        if (a + 2 < NA) {   // stage a+2 -> patch[0] while computing a+1
            const int2 lo = bb_sh[a + 2];
            const uint32_t aoff = __builtin_amdgcn_readfirstlane(
                (uint32_t)(a + 2) * 262144u +
                ((uint32_t)lo.y << 10) + ((uint32_t)lo.x << 2));
            stage10(projB + aoff, l0, goffB);
        }
        {
            const float2 cs = cs_sh[a + 1];
            const int2   lo = bb_sh[a + 1];
            compute_angle(patch[1], cs.x, cs.y, xc, yc, zf0, lo.x, lo.y, acc);
        }
        __syncthreads();
    }

    float* o0 = out + (((size_t)zb) * 128 + (y0 + threadIdx.y)) * 128
                    + (x0 + threadIdx.x);
    float* o1 = o0 + (size_t)128 * 128 * 128;   // batch 1 volume
    #pragma unroll
    for (int k = 0; k < ZPT; ++k) {
        o0[(size_t)k * (128 * 128)] = acc[k].x;
        o1[(size_t)k * (128 * 128)] = acc[k].y;
    }
}

extern "C" void kernel_launch(void* const* d_in, const int* in_sizes, int n_in,
                              void* d_out, int out_size, void* d_ws, size_t ws_size,
                              hipStream_t stream) {
    const float* proj = (const float*)d_in[0];
    float* out = (float*)d_out;
    dim3 grid(128 / ZPT, 64, 1);   // (z-groups, xy-tiles) = 1024 blocks, batch fused
    dim3 block(16, 16, 1);
    hipLaunchKernelGGL(bp_kernel, grid, block, 0, stream, proj, out);
}